// Round 9
// baseline (842.870 us; speedup 1.0000x reference)
//
#include <hip/hip_runtime.h>
#include <math.h>

#define B_     16
#define C_     64
#define HW_    512
#define KS_    15
#define HALO   7
#define PROW   528      // padded row: 8 + 512 + 8 floats (16B-aligned)
#define PADOFF 2048     // float offset of padded image inside ws (8 KB coefs)
#define YSEG   128      // rows per wave
#define NSEG   4        // 512 / YSEG

typedef float vf2 __attribute__((ext_vector_type(2)));
typedef float vf4 __attribute__((ext_vector_type(4)));

// ---------------------------------------------------------------------------
// coefs[c*32 + i]      = F2*sinc(pi*F2*(i-7))*hamming[i]   (A)
// coefs[c*32 + 16 + i] = F1*sinc(pi*F1*(i-7))*hamming[i]   (B)
// Final output = A-branch - B-branch (4 subs at store time).
// ---------------------------------------------------------------------------
__global__ void make_filters(const float* __restrict__ f1,
                             const float* __restrict__ band,
                             float* __restrict__ coefs) {
    int c = threadIdx.x;
    if (c >= C_) return;
    float F1 = f1[c];
    float F2 = F1 + fabsf(band[c]);
    const float PI = 3.14159265358979323846f;
    #pragma unroll
    for (int i = 0; i < KS_; ++i) {
        float h = 0.54f - 0.46f * cosf((2.0f * PI / 14.0f) * (float)i);
        float y1, y2;
        if (i == HALO) {
            y1 = 1.0f; y2 = 1.0f;
        } else {
            float t  = (float)(i - HALO);
            float a1 = PI * F1 * t;
            float a2 = PI * F2 * t;
            y1 = sinf(a1) / a1;
            y2 = sinf(a2) / a2;
        }
        coefs[c * 32 + i]      = F2 * y2 * h;
        coefs[c * 32 + 16 + i] = F1 * y1 * h;
    }
}

// ---------------------------------------------------------------------------
// Column-padded input copy (R5/R8-proven): xp[row*528 + gx + 8] = x[row*512+gx]
// ---------------------------------------------------------------------------
__global__ void pad_copy(const float* __restrict__ x, float* __restrict__ xp) {
    int t   = blockIdx.x * 256 + threadIdx.x;   // 8192 rows * 132 quads
    int pc4 = t % 132;
    int row = t / 132;
    const float* src = x + (size_t)row * HW_;
    int gx0 = pc4 * 4 - 8;
    float v[4];
    #pragma unroll
    for (int e = 0; e < 4; ++e) {
        int gx = gx0 + e;
        v[e] = ((unsigned)gx < (unsigned)HW_) ? src[gx] : 0.0f;
    }
    *(vf4*)(xp + (size_t)row * PROW + pc4 * 4) = *(const vf4*)v;
}

// ---------------------------------------------------------------------------
// Fused single-pass separable conv, 4 cols/thread, no LDS, PACKED FP32.
// Identical structure/indexing to the proven R8 kernel; arithmetic is
// vf2-packed across the (A,B) filter pair so the backend emits
// v_pk_fma_f32 (2x FP32 rate on gfx950):
//   h2[c]      = (hA(c0+c), hB(c0+c))   hconv: pk_fma with w-splat
//   acc2[j][c] = (vA partial, vB partial)  vconv: pk_fma, natural pack
//   store      = acc2[0][c].x - acc2[0][c].y
// ---------------------------------------------------------------------------
__global__ __launch_bounds__(64, 3)
void sinc_fused_pk(const float* __restrict__ xpad,
                   const float* __restrict__ coefs,
                   float* __restrict__ out) {
    const int lane = threadIdx.x;              // 64 threads = 1 wave
    const int bid  = blockIdx.x;
    const int ch   = bid & 63;                 // channel fastest (L2 sharing)
    const int xh   = (bid >> 6) & 1;
    const int seg  = (bid >> 7) & (NSEG - 1);
    const int b    = bid >> 9;
    const int sx   = xh * 256;
    const int y0   = seg * YSEG;
    const int c0   = sx + 4 * lane;

    // wave-uniform packed coefficients cf2[k] = (cA[k], cB[k]) -> SGPR pair
    vf2 cf2[KS_];
    #pragma unroll
    for (int i = 0; i < KS_; ++i) {
        float a = __uint_as_float(__builtin_amdgcn_readfirstlane(
                      __float_as_uint(coefs[ch * 32 + i])));
        float bq = __uint_as_float(__builtin_amdgcn_readfirstlane(
                      __float_as_uint(coefs[ch * 32 + 16 + i])));
        vf2 p; p.x = a; p.y = bq;
        cf2[i] = p;
    }

    const float* xw = xpad + (size_t)b * HW_ * PROW + c0;  // + y*PROW per row

    vf2 acc[KS_][4];                           // delay line: slot j = row y-7+j
    #pragma unroll
    for (int j = 0; j < KS_; ++j)
        #pragma unroll
        for (int c = 0; c < 4; ++c) acc[j][c] = vf2{0.f, 0.f};

    float* ob = out + ((size_t)(b * C_ + ch) * HW_) * HW_ + c0;

    #pragma unroll 1
    for (int y = y0 - HALO; y < y0 + YSEG + HALO; ++y) {   // 142 iterations
        if ((unsigned)y < (unsigned)HW_) {
            // 20-float window, 5 aligned global dwordx4 (L1/L2 hits)
            const float* p = xw + (size_t)y * PROW;
            float w[20] __attribute__((aligned(16)));
            #pragma unroll
            for (int m = 0; m < 5; ++m)
                *(vf4*)(w + 4 * m) = *(const vf4*)(p + 4 * m);
            // packed hconv: h2[c] = (sum cA[k]*w, sum cB[k]*w)
            vf2 h2[4];
            #pragma unroll
            for (int c = 0; c < 4; ++c) {
                vf2 ws; ws.x = w[c + 1]; ws.y = w[c + 1];
                h2[c] = cf2[0] * ws;
            }
            #pragma unroll
            for (int k = 1; k < KS_; ++k) {
                #pragma unroll
                for (int c = 0; c < 4; ++c) {
                    vf2 ws; ws.x = w[c + k + 1]; ws.y = w[c + k + 1];
                    h2[c] = __builtin_elementwise_fma(cf2[k], ws, h2[c]);
                }
            }
            // packed vconv delay line: slot j needs coef cf2[14-j]
            #pragma unroll
            for (int j = 0; j < KS_; ++j) {
                #pragma unroll
                for (int c = 0; c < 4; ++c)
                    acc[j][c] = __builtin_elementwise_fma(cf2[14 - j], h2[c],
                                                          acc[j][c]);
            }
        }
        // store completed output row yo = y - 7 (slot 0): A-branch - B-branch
        const int yo = y - HALO;
        if (yo >= y0) {
            vf4 st = {acc[0][0].x - acc[0][0].y,
                      acc[0][1].x - acc[0][1].y,
                      acc[0][2].x - acc[0][2].y,
                      acc[0][3].x - acc[0][3].y};
            __builtin_nontemporal_store(st, (vf4*)(ob + (size_t)yo * HW_));
        }
        // shift delay line
        #pragma unroll
        for (int j = 0; j < KS_ - 1; ++j)
            #pragma unroll
            for (int c = 0; c < 4; ++c)
                acc[j][c] = acc[j + 1][c];
        #pragma unroll
        for (int c = 0; c < 4; ++c) acc[KS_ - 1][c] = vf2{0.f, 0.f};
    }
}

extern "C" void kernel_launch(void* const* d_in, const int* in_sizes, int n_in,
                              void* d_out, int out_size, void* d_ws, size_t ws_size,
                              hipStream_t stream) {
    const float* x    = (const float*)d_in[0];
    const float* f1   = (const float*)d_in[1];
    const float* band = (const float*)d_in[2];
    float* ws   = (float*)d_ws;
    float* outp = (float*)d_out;
    float* xp   = ws + PADOFF;

    hipLaunchKernelGGL(make_filters, dim3(1), dim3(64), 0, stream,
                       f1, band, ws);
    hipLaunchKernelGGL(pad_copy, dim3(4224), dim3(256), 0, stream, x, xp);

    const int nblocks = B_ * C_ * 2 * NSEG;    // 8192 one-wave blocks
    hipLaunchKernelGGL(sinc_fused_pk, dim3(nblocks), dim3(64), 0, stream,
                       xp, ws, outp);
}